// Round 8
// baseline (1280.136 us; speedup 1.0000x reference)
//
#include <hip/hip_runtime.h>
#include <stdint.h>

typedef short bf8 __attribute__((ext_vector_type(8)));   // 8 bf16 (4 VGPRs)
typedef float f4  __attribute__((ext_vector_type(4)));   // MFMA acc
typedef unsigned short u16;
typedef unsigned int   u32;
typedef unsigned long long u64;
typedef unsigned long long u64x2 __attribute__((ext_vector_type(2)));

#define LOG2E 1.4426950408889634f

__device__ __forceinline__ u16 f2bf(float f){
  uint32_t u = __builtin_bit_cast(uint32_t, f);
  u += 0x7fffu + ((u >> 16) & 1u);
  return (u16)(u >> 16);
}
// sigmoid of value pre-scaled by log2e: 1/(1+2^-a)
__device__ __forceinline__ float sigm_ps(float a){
  return __builtin_amdgcn_rcpf(1.0f + __builtin_amdgcn_exp2f(-a));
}
// LDS-only barrier: don't drain vmcnt (global loads/stores stay in flight)
__device__ __forceinline__ void bar_lds(){
  asm volatile("s_waitcnt lgkmcnt(0)\n\ts_barrier" ::: "memory");
}

__device__ __forceinline__ void cell2(const float g0[4], const float g1[4],
                                      float& c0, float& c1, float& hv0, float& hv1){
  float i0 = sigm_ps(g0[0]), f0 = sigm_ps(g0[1]);
  float G0 = 2.f*sigm_ps(g0[2]) - 1.f;
  float o0 = sigm_ps(g0[3]);
  c0 = f0*c0 + i0*G0;
  hv0 = o0 * (2.f*sigm_ps(c0*(2.f*LOG2E)) - 1.f);
  float i1 = sigm_ps(g1[0]), f1 = sigm_ps(g1[1]);
  float G1 = 2.f*sigm_ps(g1[2]) - 1.f;
  float o1 = sigm_ps(g1[3]);
  c1 = f1*c1 + i1*G1;
  hv1 = o1 * (2.f*sigm_ps(c1*(2.f*LOG2E)) - 1.f);
}

// ---------------------------------------------------------------------------
// Prep: prescaled bf16 weights W0c[512][160]=[Whh0|Wih0|0], W1c[512][256]=
// [Whh1|Wih1]; rows scaled log2e (i,f,o) / 2*log2e (g); prescaled biases;
// zero the 64 producer flags (ws is poisoned 0xAA before every launch!).
// ---------------------------------------------------------------------------
__global__ void prep_kernel(const float* __restrict__ Wih0, const float* __restrict__ Whh0,
                            const float* __restrict__ bih0, const float* __restrict__ bhh0,
                            const float* __restrict__ Wih1, const float* __restrict__ Whh1,
                            const float* __restrict__ bih1, const float* __restrict__ bhh1,
                            u16* __restrict__ W0c, u16* __restrict__ W1c,
                            float* __restrict__ bias0, float* __restrict__ bias1,
                            int* __restrict__ flags){
  int g = blockIdx.x;      // gate row 0..511
  int t = threadIdx.x;     // 0..63
  float s = (g >= 256 && g < 384) ? 2.0f * LOG2E : LOG2E;
  for(int k = t; k < 160; k += 64){
    float v = 0.0f;
    if(k < 128)      v = Whh0[g*128 + k];
    else if(k < 146) v = Wih0[g*18 + (k-128)];
    W0c[g*160 + k] = f2bf(v * s);
  }
  for(int k = t; k < 256; k += 64){
    float v = (k < 128) ? Whh1[g*128 + k] : Wih1[g*128 + (k-128)];
    W1c[g*256 + k] = f2bf(v * s);
  }
  if(t == 0){
    bias0[g] = (bih0[g] + bhh0[g]) * s;
    bias1[g] = (bih1[g] + bhh1[g]) * s;
  }
  if(g == 0) flags[t] = 0;   // 64 producer rowblock flags
}

// ===========================================================================
// Fused 2-layer LSTM on disjoint CUs. 128 blocks x 512 thr, 8 batch rows
// per block. bid<64: L0 producer; bid>=64: L1 consumer (same rowblock rb).
// Gate-major MFMA: A = weights (static VGPR frags, M=16-gate tiles),
// B = state (N=16; cols 8-15 duplicate rows 0-7). acc[q][r] at lane
// (quad,l15) = gate q, comp j=16w+4*quad+r, row l15&7 — upper l15 lanes
// hold DUPLICATE valid values, so the update select is per-lane (cndmask),
// no cross-lane moves. LDS hbT[buf][kc][8][8] conflict-free (R6 scheme).
// Cross-layer h1 via agent-scope (LLC-coherent) stores/loads; flag
// handshake every 8 steps (producer __syncthreads-drain amortized).
// ===========================================================================
__global__ __launch_bounds__(512, 2)
void lstm_fused(const u16* __restrict__ Wc0, const u16* __restrict__ Wc1,
                const float* __restrict__ bias0, const float* __restrict__ bias1,
                const float* __restrict__ xin,   // (512,512,18) f32
                u16* __restrict__ h1g,           // [512 t][512 row][128] bf16
                int* __restrict__ flags,         // [64]
                const float* __restrict__ Wfc1, const float* __restrict__ bfc1,
                const float* __restrict__ Wfc2, const float* __restrict__ bfc2,
                float* __restrict__ out)         // (512,) f32
{
  __shared__ __align__(16) u16  hbT[2][20][8][8];  // L0: h(16kc)+x(4kc); L1: 16kc
  __shared__ __align__(16) float ffin[8][132];

  const int tid  = threadIdx.x;
  const int wave = tid >> 6;
  const int lane = tid & 63;
  const int quad = lane >> 4;
  const int l15  = lane & 15;
  const bool up  = (l15 >= 8);
  const int row  = l15 & 7;
  const bool isL0 = (blockIdx.x < 64);
  const int rb   = isL0 ? blockIdx.x : (blockIdx.x - 64);
  const int rowbase = rb * 8;
  const int kc = 2*wave + (quad>>1);
  const int eo = 4*(quad&1) + (up ? 2 : 0);
  const int jc = 16*wave + 4*quad + (up ? 2 : 0);

  for(int i = tid; i < 2*20*8*8; i += 512) ((u16*)hbT)[i] = 0;

  if(isL0){
    // ---------------- L0 producer: K=160=[h0|x|0], KT=5 ------------------
    bf8 A[4][5];
#pragma unroll
    for(int q = 0; q < 4; q++){
      const u16* wp = Wc0 + (u64)(128*q + 16*wave + l15)*160 + quad*8;
#pragma unroll
      for(int kt = 0; kt < 5; kt++) A[q][kt] = *(const bf8*)(wp + kt*32);
    }
    f4 bini[4];
#pragma unroll
    for(int q = 0; q < 4; q++) bini[q] = *(const f4*)(bias0 + 128*q + 16*wave + quad*4);
    float c0 = 0.f, c1 = 0.f;

    __syncthreads();
    int sr = 0, sk = 0;
    if(tid < 144){ sr = tid/18; sk = tid - 18*sr; }
    if(tid < 144)
      hbT[0][16+(sk>>3)][sr][sk&7] = f2bf(xin[((u64)(rowbase+sr)*512)*18 + sk]);
    __syncthreads();

    for(int t = 0; t < 512; t++){
      const int cur = t & 1, nxt = cur ^ 1;
      float xv = 0.f;
      if(tid < 144 && t < 511)
        xv = xin[((u64)(rowbase+sr)*512 + (t+1))*18 + sk];

      bf8 B[5];
#pragma unroll
      for(int kt = 0; kt < 5; kt++) B[kt] = *(const bf8*)&hbT[cur][kt*4+quad][row][0];

      f4 acc[4];
#pragma unroll
      for(int q = 0; q < 4; q++) acc[q] = bini[q];
#pragma unroll
      for(int kt = 0; kt < 5; kt++){
#pragma unroll
        for(int q = 0; q < 4; q++)
          acc[q] = __builtin_amdgcn_mfma_f32_16x16x32_bf16(A[q][kt], B[kt], acc[q], 0,0,0);
      }

      // per-lane select (upper lanes hold duplicate valid rows)
      float g0[4], g1[4];
#pragma unroll
      for(int q = 0; q < 4; q++){
        g0[q] = up ? acc[q][2] : acc[q][0];
        g1[q] = up ? acc[q][3] : acc[q][1];
      }
      float hv0, hv1;
      cell2(g0, g1, c0, c1, hv0, hv1);
      u32 hpair = (u32)f2bf(hv0) | ((u32)f2bf(hv1) << 16);
      *(u32*)&hbT[nxt][kc][row][eo] = hpair;
      // publish h1(t): agent-scope (LLC-coherent), completion NOT waited here
      __hip_atomic_store((u32*)(h1g + ((u64)t*512 + rowbase + row)*128 + jc), hpair,
                         __ATOMIC_RELAXED, __HIP_MEMORY_SCOPE_AGENT);
      if(tid < 144 && t < 511) hbT[nxt][16+(sk>>3)][sr][sk&7] = f2bf(xv);

      if((t & 7) == 7){
        __syncthreads();   // drains every wave's vmcnt -> h1(<=t) at LLC
        if(tid == 0)
          __hip_atomic_store(flags + rb, t + 1,
                             __ATOMIC_RELAXED, __HIP_MEMORY_SCOPE_AGENT);
      } else {
        bar_lds();
      }
    }
  } else {
    // ---------------- L1 consumer: K=256=[h2|h1], KT=8 --------------------
    bf8 A[4][8];
#pragma unroll
    for(int q = 0; q < 4; q++){
      const u16* wp = Wc1 + (u64)(128*q + 16*wave + l15)*256 + quad*8;
#pragma unroll
      for(int kt = 0; kt < 8; kt++) A[q][kt] = *(const bf8*)(wp + kt*32);
    }
    f4 bini[4];
#pragma unroll
    for(int q = 0; q < 4; q++) bini[q] = *(const f4*)(bias1 + 128*q + 16*wave + quad*4);
    float c0 = 0.f, c1 = 0.f;

    const u64* hp64 = (const u64*)h1g + ((u64)rowbase + row)*32 + 2*quad;
    __syncthreads();

    // bootstrap: wait for first flag (producer step 7), load h1(0)
    int Fv = 0;
    while(Fv < 1){
      Fv = __hip_atomic_load(flags + rb, __ATOMIC_RELAXED, __HIP_MEMORY_SCOPE_AGENT);
      if(Fv < 1) __builtin_amdgcn_s_sleep(8);
    }
    bf8 h1f[4];
#pragma unroll
    for(int kh = 0; kh < 4; kh++){
      u64x2 v;
      v.x = __hip_atomic_load(hp64 + 8*kh,     __ATOMIC_RELAXED, __HIP_MEMORY_SCOPE_AGENT);
      v.y = __hip_atomic_load(hp64 + 8*kh + 1, __ATOMIC_RELAXED, __HIP_MEMORY_SCOPE_AGENT);
      h1f[kh] = __builtin_bit_cast(bf8, v);
    }

    float hv0 = 0.f, hv1 = 0.f;
    for(int t = 0; t < 512; t++){
      const int cur = t & 1, nxt = cur ^ 1;
      u64 nraw[8];
      if(t < 511){
        const int need = t + 2;
        while(Fv < need){   // steady state: register compare only
          Fv = __hip_atomic_load(flags + rb, __ATOMIC_RELAXED, __HIP_MEMORY_SCOPE_AGENT);
          if(Fv < need) __builtin_amdgcn_s_sleep(2);
        }
        const u64* p = hp64 + (u64)(t+1)*16384;
#pragma unroll
        for(int kh = 0; kh < 4; kh++){
          nraw[2*kh]   = __hip_atomic_load(p + 8*kh,     __ATOMIC_RELAXED, __HIP_MEMORY_SCOPE_AGENT);
          nraw[2*kh+1] = __hip_atomic_load(p + 8*kh + 1, __ATOMIC_RELAXED, __HIP_MEMORY_SCOPE_AGENT);
        }
      }

      bf8 B[4];
#pragma unroll
      for(int kt = 0; kt < 4; kt++) B[kt] = *(const bf8*)&hbT[cur][kt*4+quad][row][0];

      f4 acc[4];
#pragma unroll
      for(int q = 0; q < 4; q++) acc[q] = bini[q];
#pragma unroll
      for(int kt = 0; kt < 4; kt++){
#pragma unroll
        for(int q = 0; q < 4; q++)
          acc[q] = __builtin_amdgcn_mfma_f32_16x16x32_bf16(A[q][kt], B[kt], acc[q], 0,0,0);
      }
#pragma unroll
      for(int kh = 0; kh < 4; kh++){
#pragma unroll
        for(int q = 0; q < 4; q++)
          acc[q] = __builtin_amdgcn_mfma_f32_16x16x32_bf16(A[q][4+kh], h1f[kh], acc[q], 0,0,0);
      }

      float g0[4], g1[4];
#pragma unroll
      for(int q = 0; q < 4; q++){
        g0[q] = up ? acc[q][2] : acc[q][0];
        g1[q] = up ? acc[q][3] : acc[q][1];
      }
      cell2(g0, g1, c0, c1, hv0, hv1);
      u32 hpair = (u32)f2bf(hv0) | ((u32)f2bf(hv1) << 16);
      *(u32*)&hbT[nxt][kc][row][eo] = hpair;
      bar_lds();
      if(t < 511){
#pragma unroll
        for(int kh = 0; kh < 4; kh++){
          u64x2 v; v.x = nraw[2*kh]; v.y = nraw[2*kh+1];
          h1f[kh] = __builtin_bit_cast(bf8, v);
        }
      }
    }

    // final h2 (f32) -> LDS; fused FC head
    ffin[row][jc]   = hv0;
    ffin[row][jc+1] = hv1;
    __syncthreads();
    {
      int r = wave;
      float s = bfc1[lane];
      const float* wrow = Wfc1 + lane*128;
      for(int j = 0; j < 128; j++) s = fmaf(wrow[j], ffin[r][j], s);
      float term = fmaxf(s, 0.f) * Wfc2[lane];
#pragma unroll
      for(int off = 32; off > 0; off >>= 1) term += __shfl_down(term, off);
      if(lane == 0) out[rowbase + r] = sigm_ps((term + bfc2[0]) * LOG2E);
    }
  }
}

// ---------------------------------------------------------------------------
extern "C" void kernel_launch(void* const* d_in, const int* in_sizes, int n_in,
                              void* d_out, int out_size, void* d_ws, size_t ws_size,
                              hipStream_t stream){
  const float* x    = (const float*)d_in[0];
  const float* Wih0 = (const float*)d_in[1];
  const float* Whh0 = (const float*)d_in[2];
  const float* bih0 = (const float*)d_in[3];
  const float* bhh0 = (const float*)d_in[4];
  const float* Wih1 = (const float*)d_in[5];
  const float* Whh1 = (const float*)d_in[6];
  const float* bih1 = (const float*)d_in[7];
  const float* bhh1 = (const float*)d_in[8];
  const float* Wfc1 = (const float*)d_in[9];
  const float* bfc1 = (const float*)d_in[10];
  const float* Wfc2 = (const float*)d_in[11];
  const float* bfc2 = (const float*)d_in[12];

  char* ws = (char*)d_ws;
  u16*   W0c   = (u16*)(ws);                       // 512*160*2 = 163840 B
  u16*   W1c   = (u16*)(ws + 163840);              // 512*256*2 = 262144 B
  float* bias0 = (float*)(ws + 163840 + 262144);   // 2048 B
  float* bias1 = bias0 + 512;                      // 2048 B
  int*   flags = (int*)(ws + 163840 + 262144 + 4096);  // 256 B (pad 1024)
  u16*   h1g   = (u16*)(ws + 163840 + 262144 + 4096 + 1024); // 64 MiB

  prep_kernel<<<dim3(512), dim3(64), 0, stream>>>(Wih0, Whh0, bih0, bhh0,
                                                  Wih1, Whh1, bih1, bhh1,
                                                  W0c, W1c, bias0, bias1, flags);

  lstm_fused<<<dim3(128), dim3(512), 0, stream>>>(
      W0c, W1c, bias0, bias1, x, h1g, flags,
      Wfc1, bfc1, Wfc2, bfc2, (float*)d_out);
}